// Round 3
// baseline (308.481 us; speedup 1.0000x reference)
//
#include <hip/hip_runtime.h>
#include <hip/hip_bf16.h>
#include <cstdio>

typedef __bf16  bf16x8 __attribute__((ext_vector_type(8)));
typedef float   f32x4  __attribute__((ext_vector_type(4)));
typedef unsigned short u16;
typedef u16     u16x8  __attribute__((ext_vector_type(8)));

// ---------- helpers ----------

__device__ __forceinline__ void gld_lds16(const void* g, void* l) {
  // async global->LDS, 16B per lane; LDS dest is wave-uniform base + lane*16
  __builtin_amdgcn_global_load_lds(
      (const __attribute__((address_space(1))) unsigned int*)g,
      (__attribute__((address_space(3))) unsigned int*)l,
      16, 0, 0);
}

__device__ __forceinline__ u16 f2bf(float f) {
  union { float f; unsigned int u; } c{f};
  unsigned int u = c.u;
  u += 0x7fffu + ((u >> 16) & 1u);   // round-to-nearest-even
  return (u16)(u >> 16);
}

__device__ __forceinline__ float bf2f(u16 h) {
  union { unsigned int u; float f; } c{(unsigned int)h << 16};
  return c.f;
}

// ---------- prep: cast x -> bf16  AND  pack/transpose weights ----------
// grid: [0,4096) cast blocks, [4096, 4096+3072) weight-tile blocks

__global__ __launch_bounds__(256) void prep_kernel(const float* __restrict__ x,
                                                   u16* __restrict__ xbf,
                                                   const float* __restrict__ w,
                                                   u16* __restrict__ wt) {
  __shared__ float tile[32][33];
  const int bid = blockIdx.x;
  if (bid < 4096) {
    const int i = (bid * 256 + threadIdx.x) * 8;
    float4 a = *(const float4*)(x + i);
    float4 b = *(const float4*)(x + i + 4);
    u16x8 r;
    r[0] = f2bf(a.x); r[1] = f2bf(a.y); r[2] = f2bf(a.z); r[3] = f2bf(a.w);
    r[4] = f2bf(b.x); r[5] = f2bf(b.y); r[6] = f2bf(b.z); r[7] = f2bf(b.w);
    *(u16x8*)(xbf + i) = r;
  } else {
    // WT[s][e][d] = w[s][d][e], s in 0..2
    const int b2 = bid - 4096;
    const int s = b2 >> 10, r = b2 & 1023;
    const int e0 = (r & 31) * 32, d0 = (r >> 5) * 32;
    const int tx = threadIdx.x & 31, ty = threadIdx.x >> 5;
    const float* in = w + (size_t)s * 1048576;
#pragma unroll
    for (int j = 0; j < 4; ++j)
      tile[ty + j * 8][tx] = in[(size_t)(d0 + ty + j * 8) * 1024 + e0 + tx];
    __syncthreads();
    u16* o = wt + (size_t)s * 1048576;
#pragma unroll
    for (int j = 0; j < 4; ++j)
      o[(size_t)(e0 + ty + j * 8) * 1024 + d0 + tx] = f2bf(tile[tx][ty + j * 8]);
  }
}

// ---------- BT-GEMM: C[M,N] = A[M,K] * B[N,K]^T, bf16 in, fp32 acc ----------
// grid: (N/128, M/128, batch); block 256 (4 waves, 2x2 of 64x64)
//
// LDS tile: 128 rows x 32 bf16 (64 B/row, unpadded for global_load_lds).
// XOR-swizzle (16B chunk c of row r at slot c ^ ((r>>1)&3)) -> 0 bank conflicts.
//
// Epilogues:
//  EPI_QKV: n0<2048 -> bf16 store to WQKV; n0>=2048 -> transposed bf16 store to VT
//  EPI_QK : store P' = exp(acc/32) bf16 (unnormalized), atomicAdd fp32 row sums
//  EPI_PV : fp32 store of acc / rowsum[row]

enum { EPI_QKV = 0, EPI_QK = 1, EPI_PV = 2 };

template <int EPI>
__global__ __launch_bounds__(256)
void gemm_bt(const u16* __restrict__ A, const u16* __restrict__ B,
             void* __restrict__ Cv, int K, int lda, int ldb, int ldc,
             long sA, long sB, long sC,
             float* __restrict__ rowsum, u16* __restrict__ vt) {
  __shared__ __align__(16) u16 As[128 * 32];
  __shared__ __align__(16) u16 Bs[128 * 32];
  const int t = threadIdx.x;
  const int w = t >> 6, l = t & 63;
  const int bz = blockIdx.z;
  const u16* Ab = A + (long)bz * sA;
  const u16* Bb = B + (long)bz * sB;
  const int m0 = blockIdx.y * 128, n0 = blockIdx.x * 128;
  const int wm = w & 1, wn = w >> 1;
  const int lr = l & 15, lq = l >> 4;
  const int srow = l >> 2;                             // staging: row within 16-row chunk
  const int scol = ((l & 3) ^ ((l >> 3) & 3)) * 8;     // staging: swizzled global chunk
  const int fsw = (l >> 1) & 3;                        // read-side swizzle for row lr

  f32x4 acc[4][4] = {};

  for (int k0 = 0; k0 < K; k0 += 32) {
    __syncthreads();
#pragma unroll
    for (int c = 0; c < 2; ++c) {
      const int rb = (w * 2 + c) * 16;  // 4 waves x 2 calls x 16 rows = 128
      gld_lds16(Ab + (long)(m0 + rb + srow) * lda + k0 + scol, (void*)(As + rb * 32));
      gld_lds16(Bb + (long)(n0 + rb + srow) * ldb + k0 + scol, (void*)(Bs + rb * 32));
    }
    __syncthreads();
    bf16x8 af[4], bfr[4];
#pragma unroll
    for (int i = 0; i < 4; ++i) {
      af[i]  = *(const bf16x8*)(As + (wm * 64 + i * 16 + lr) * 32 + (lq ^ fsw) * 8);
      bfr[i] = *(const bf16x8*)(Bs + (wn * 64 + i * 16 + lr) * 32 + (lq ^ fsw) * 8);
    }
#pragma unroll
    for (int mi = 0; mi < 4; ++mi)
#pragma unroll
      for (int ni = 0; ni < 4; ++ni)
        acc[mi][ni] = __builtin_amdgcn_mfma_f32_16x16x32_bf16(af[mi], bfr[ni], acc[mi][ni], 0, 0, 0);
  }

  const bool vslice = (EPI == EPI_QKV) && (n0 >= 2048);

#pragma unroll
  for (int mi = 0; mi < 4; ++mi) {
#pragma unroll
    for (int i = 0; i < 4; ++i) {
      const int row = m0 + wm * 64 + mi * 16 + lq * 4 + i;
      float inv;
      if (EPI == EPI_PV) inv = 1.0f / rowsum[bz * 2048 + row];
      float rs = 0.f;
#pragma unroll
      for (int ni = 0; ni < 4; ++ni) {
        const int col = n0 + wn * 64 + ni * 16 + lr;
        const float val = acc[mi][ni][i];
        if (EPI == EPI_QKV) {
          if (vslice) {
            // VT[b][e][k] = V[b][k][e];  b = row>>11, k = row&2047, e = col-2048
            const long b = row >> 11, k = row & 2047, e = col - 2048;
            vt[b * 2097152 + e * 2048 + k] = f2bf(val);
          } else {
            ((u16*)Cv)[(long)row * ldc + col] = f2bf(val);
          }
        } else if (EPI == EPI_QK) {
          const u16 h = f2bf(__expf(val * 0.03125f));  // unnormalized prob, bf16
          ((u16*)Cv)[(long)bz * sC + (long)row * ldc + col] = h;
          rs += bf2f(h);                                // sum the rounded value
        } else {  // EPI_PV
          ((float*)Cv)[(long)bz * sC + (long)row * ldc + col] = val * inv;
        }
      }
      if (EPI == EPI_QK) {
        // reduce over the 16 lanes (lr) that share this row
        rs += __shfl_xor(rs, 1, 64);
        rs += __shfl_xor(rs, 2, 64);
        rs += __shfl_xor(rs, 4, 64);
        rs += __shfl_xor(rs, 8, 64);
        if (lr == 0) atomicAdd(rowsum + bz * 2048 + row, rs);
      }
    }
  }
}

// ---------- launch ----------

extern "C" void kernel_launch(void* const* d_in, const int* in_sizes, int n_in,
                              void* d_out, int out_size, void* d_ws, size_t ws_size,
                              hipStream_t stream) {
  (void)in_sizes; (void)n_in; (void)out_size;
  const float* x    = (const float*)d_in[0];
  const float* kern = (const float*)d_in[1];
  float* out = (float*)d_out;
  char* ws = (char*)d_ws;
  const size_t MB = 1024 * 1024;
  u16*   xbf  = (u16*)(ws);              // 16 MB: [8192][1024] bf16
  u16*   WT   = (u16*)(ws + 16 * MB);    //  6 MB: [3][1024][1024] bf16
  u16*   WQKV = (u16*)(ws + 22 * MB);    // 48 MB: [8192][3072] bf16 (Q|K|V; V cols unused)
  u16*   VT   = (u16*)(ws + 70 * MB);    // 16 MB: [4][1024][2048] bf16
  u16*   SP   = (u16*)(ws + 86 * MB);    // 32 MB: [4][2048][2048] bf16 unnormalized probs
  float* RS   = (float*)(ws + 118 * MB); // 32 KB: [4][2048] fp32 row sums
  if (ws_size < 118 * MB + 32768)
    fprintf(stderr, "WARNING: ws_size %zu too small\n", ws_size);

  prep_kernel<<<4096 + 3072, 256, 0, stream>>>(x, xbf, kern, WT);
  hipMemsetAsync(RS, 0, 8192 * sizeof(float), stream);
  // WQKV[m, s*1024+e] = xbf[m,:] . WT[s*1024+e,:]   (V slice diverted to VT, transposed)
  gemm_bt<EPI_QKV><<<dim3(24, 64, 1), 256, 0, stream>>>(
      xbf, WT, WQKV, 1024, 1024, 1024, 3072, 0, 0, 0, nullptr, VT);
  // P'[b][q][k] = exp((Q[b][q,:].K[b][k,:])/32), rowsum accumulated
  gemm_bt<EPI_QK><<<dim3(16, 16, 4), 256, 0, stream>>>(
      WQKV, WQKV + 1024, SP, 1024, 3072, 3072, 2048,
      2048L * 3072, 2048L * 3072, 2048L * 2048, RS, nullptr);
  // out[b][q][e] = (P'[b][q,:] . VT[b][e,:]) / rowsum[b][q]
  gemm_bt<EPI_PV><<<dim3(8, 16, 4), 256, 0, stream>>>(
      SP, VT, out, 2048, 2048, 2048, 1024,
      2048L * 2048, 1024L * 2048, 2048L * 1024, RS, nullptr);
}

// Round 4
// 293.191 us; speedup vs baseline: 1.0521x; 1.0521x over previous
//
#include <hip/hip_runtime.h>
#include <hip/hip_bf16.h>
#include <cstdio>

typedef __bf16  bf16x8 __attribute__((ext_vector_type(8)));
typedef float   f32x4  __attribute__((ext_vector_type(4)));
typedef unsigned short u16;
typedef u16     u16x8  __attribute__((ext_vector_type(8)));

// ---------- helpers ----------

__device__ __forceinline__ void gld_lds16(const void* g, void* l) {
  // async global->LDS, 16B per lane; LDS dest is wave-uniform base + lane*16
  __builtin_amdgcn_global_load_lds(
      (const __attribute__((address_space(1))) unsigned int*)g,
      (__attribute__((address_space(3))) unsigned int*)l,
      16, 0, 0);
}

__device__ __forceinline__ u16 f2bf(float f) {
  union { float f; unsigned int u; } c{f};
  unsigned int u = c.u;
  u += 0x7fffu + ((u >> 16) & 1u);   // round-to-nearest-even
  return (u16)(u >> 16);
}

__device__ __forceinline__ float bf2f(u16 h) {
  union { unsigned int u; float f; } c{(unsigned int)h << 16};
  return c.f;
}

// ---------- prep: cast x -> bf16, pack/transpose weights, zero rowsums ----------
// grid: [0,4096) cast blocks, [4096,7168) weight tiles, 7168 = RS zero

__global__ __launch_bounds__(256) void prep_kernel(const float* __restrict__ x,
                                                   u16* __restrict__ xbf,
                                                   const float* __restrict__ w,
                                                   u16* __restrict__ wt,
                                                   float* __restrict__ rs) {
  __shared__ float tile[32][33];
  const int bid = blockIdx.x;
  if (bid < 4096) {
    const int i = (bid * 256 + threadIdx.x) * 8;
    float4 a = *(const float4*)(x + i);
    float4 b = *(const float4*)(x + i + 4);
    u16x8 r;
    r[0] = f2bf(a.x); r[1] = f2bf(a.y); r[2] = f2bf(a.z); r[3] = f2bf(a.w);
    r[4] = f2bf(b.x); r[5] = f2bf(b.y); r[6] = f2bf(b.z); r[7] = f2bf(b.w);
    *(u16x8*)(xbf + i) = r;
  } else if (bid < 7168) {
    // WT[s][e][d] = w[s][d][e], s in 0..2
    const int b2 = bid - 4096;
    const int s = b2 >> 10, r = b2 & 1023;
    const int e0 = (r & 31) * 32, d0 = (r >> 5) * 32;
    const int tx = threadIdx.x & 31, ty = threadIdx.x >> 5;
    const float* in = w + (size_t)s * 1048576;
#pragma unroll
    for (int j = 0; j < 4; ++j)
      tile[ty + j * 8][tx] = in[(size_t)(d0 + ty + j * 8) * 1024 + e0 + tx];
    __syncthreads();
    u16* o = wt + (size_t)s * 1048576;
#pragma unroll
    for (int j = 0; j < 4; ++j)
      o[(size_t)(e0 + ty + j * 8) * 1024 + d0 + tx] = f2bf(tile[tx][ty + j * 8]);
  } else {
    const float4 z = {0.f, 0.f, 0.f, 0.f};
#pragma unroll
    for (int j = 0; j < 8; ++j)
      ((float4*)rs)[threadIdx.x + j * 256] = z;  // 8192 floats
  }
}

// V compact [4b][2048k][1024e] -> VT [4b][1024e][2048k]
__global__ void transpose_v_kernel(const u16* __restrict__ vc, u16* __restrict__ vt) {
  __shared__ u16 tile[32][33];
  const int b = blockIdx.z, e0 = blockIdx.x * 32, k0 = blockIdx.y * 32;
  const int tx = threadIdx.x, ty = threadIdx.y;
  const u16* in = vc + (size_t)b * 2048 * 1024;
#pragma unroll
  for (int j = 0; j < 4; ++j)
    tile[ty + j * 8][tx] = in[(size_t)(k0 + ty + j * 8) * 1024 + e0 + tx];
  __syncthreads();
  u16* o = vt + (size_t)b * 1024 * 2048;
#pragma unroll
  for (int j = 0; j < 4; ++j)
    o[(size_t)(e0 + ty + j * 8) * 2048 + k0 + tx] = tile[tx][ty + j * 8];
}

// ---------- BT-GEMM: C[M,N] = A[M,K] * B[N,K]^T, bf16 in, fp32 acc ----------
// grid: (N/128, M/128, batch); block 256 (4 waves, 2x2 of 64x64)
//
// LDS tile: 128 rows x 32 bf16 (64 B/row, unpadded for global_load_lds).
// XOR-swizzle (16B chunk c of row r at slot c ^ ((r>>1)&3)) -> 0 bank conflicts.
//
// Epilogues:
//  EPI_QKV: block-uniform split on n0>>10 -> dense bf16 stores to Qc/Kc/Vc (ld 1024)
//  EPI_QK : store P' = exp(acc/32) bf16 (unnormalized), atomicAdd fp32 row sums
//  EPI_PV : fp32 store of acc / rowsum[row]

enum { EPI_QKV = 0, EPI_QK = 1, EPI_PV = 2 };

template <int EPI>
__global__ __launch_bounds__(256)
void gemm_bt(const u16* __restrict__ A, const u16* __restrict__ B,
             void* __restrict__ Cv, int K, int lda, int ldb, int ldc,
             long sA, long sB, long sC,
             float* __restrict__ rowsum, u16* __restrict__ auxK, u16* __restrict__ auxV) {
  __shared__ __align__(16) u16 As[128 * 32];
  __shared__ __align__(16) u16 Bs[128 * 32];
  const int t = threadIdx.x;
  const int w = t >> 6, l = t & 63;
  const int bz = blockIdx.z;
  const u16* Ab = A + (long)bz * sA;
  const u16* Bb = B + (long)bz * sB;
  const int m0 = blockIdx.y * 128, n0 = blockIdx.x * 128;
  const int wm = w & 1, wn = w >> 1;
  const int lr = l & 15, lq = l >> 4;
  const int srow = l >> 2;                             // staging: row within 16-row chunk
  const int scol = ((l & 3) ^ ((l >> 3) & 3)) * 8;     // staging: swizzled global chunk
  const int fsw = (l >> 1) & 3;                        // read-side swizzle for row lr

  f32x4 acc[4][4] = {};

  for (int k0 = 0; k0 < K; k0 += 32) {
    __syncthreads();
#pragma unroll
    for (int c = 0; c < 2; ++c) {
      const int rb = (w * 2 + c) * 16;  // 4 waves x 2 calls x 16 rows = 128
      gld_lds16(Ab + (long)(m0 + rb + srow) * lda + k0 + scol, (void*)(As + rb * 32));
      gld_lds16(Bb + (long)(n0 + rb + srow) * ldb + k0 + scol, (void*)(Bs + rb * 32));
    }
    __syncthreads();
    bf16x8 af[4], bfr[4];
#pragma unroll
    for (int i = 0; i < 4; ++i) {
      af[i]  = *(const bf16x8*)(As + (wm * 64 + i * 16 + lr) * 32 + (lq ^ fsw) * 8);
      bfr[i] = *(const bf16x8*)(Bs + (wn * 64 + i * 16 + lr) * 32 + (lq ^ fsw) * 8);
    }
#pragma unroll
    for (int mi = 0; mi < 4; ++mi)
#pragma unroll
      for (int ni = 0; ni < 4; ++ni)
        acc[mi][ni] = __builtin_amdgcn_mfma_f32_16x16x32_bf16(af[mi], bfr[ni], acc[mi][ni], 0, 0, 0);
  }

  // block-uniform output target for EPI_QKV
  u16* qkv_out = nullptr;
  int nl0 = 0;
  if (EPI == EPI_QKV) {
    const int s = n0 >> 10;
    qkv_out = (s == 0) ? (u16*)Cv : (s == 1 ? auxK : auxV);
    nl0 = n0 & 1023;
  }

#pragma unroll
  for (int mi = 0; mi < 4; ++mi) {
#pragma unroll
    for (int i = 0; i < 4; ++i) {
      const int row = m0 + wm * 64 + mi * 16 + lq * 4 + i;
      float inv;
      if (EPI == EPI_PV) inv = 1.0f / rowsum[bz * 2048 + row];
      float rs = 0.f;
#pragma unroll
      for (int ni = 0; ni < 4; ++ni) {
        const float val = acc[mi][ni][i];
        if (EPI == EPI_QKV) {
          const int col_l = nl0 + wn * 64 + ni * 16 + lr;
          qkv_out[(long)row * 1024 + col_l] = f2bf(val);
        } else if (EPI == EPI_QK) {
          const int col = n0 + wn * 64 + ni * 16 + lr;
          const u16 h = f2bf(__expf(val * 0.03125f));  // unnormalized prob, bf16
          ((u16*)Cv)[(long)bz * sC + (long)row * ldc + col] = h;
          rs += bf2f(h);                                // sum the rounded value
        } else {  // EPI_PV
          const int col = n0 + wn * 64 + ni * 16 + lr;
          ((float*)Cv)[(long)bz * sC + (long)row * ldc + col] = val * inv;
        }
      }
      if (EPI == EPI_QK) {
        // reduce over the 16 lanes (lr) that share this row
        rs += __shfl_xor(rs, 1, 64);
        rs += __shfl_xor(rs, 2, 64);
        rs += __shfl_xor(rs, 4, 64);
        rs += __shfl_xor(rs, 8, 64);
        if (lr == 0) atomicAdd(rowsum + bz * 2048 + row, rs);
      }
    }
  }
}

// ---------- launch ----------

extern "C" void kernel_launch(void* const* d_in, const int* in_sizes, int n_in,
                              void* d_out, int out_size, void* d_ws, size_t ws_size,
                              hipStream_t stream) {
  (void)in_sizes; (void)n_in; (void)out_size;
  const float* x    = (const float*)d_in[0];
  const float* kern = (const float*)d_in[1];
  float* out = (float*)d_out;
  char* ws = (char*)d_ws;
  const size_t MB = 1024 * 1024;
  u16*   xbf  = (u16*)(ws);              // 16 MB: [8192][1024] bf16
  u16*   WT   = (u16*)(ws + 16 * MB);    //  6 MB: [3][1024][1024] bf16
  u16*   Qc   = (u16*)(ws + 22 * MB);    // 16 MB: [8192][1024] bf16
  u16*   Kc   = (u16*)(ws + 38 * MB);    // 16 MB: [8192][1024] bf16
  u16*   Vc   = (u16*)(ws + 54 * MB);    // 16 MB: [8192][1024] bf16
  u16*   VT   = (u16*)(ws + 70 * MB);    // 16 MB: [4][1024][2048] bf16
  u16*   SP   = (u16*)(ws + 86 * MB);    // 32 MB: [4][2048][2048] bf16 unnormalized probs
  float* RS   = (float*)(ws + 118 * MB); // 32 KB: [4][2048] fp32 row sums
  if (ws_size < 118 * MB + 32768)
    fprintf(stderr, "WARNING: ws_size %zu too small\n", ws_size);

  prep_kernel<<<7169, 256, 0, stream>>>(x, xbf, kern, WT, RS);
  // [Q|K|V][m][e] = xbf[m,:] . WT[s*1024+e,:]  (dense per-slice outputs)
  gemm_bt<EPI_QKV><<<dim3(24, 64, 1), 256, 0, stream>>>(
      xbf, WT, Qc, 1024, 1024, 1024, 1024, 0, 0, 0, nullptr, Kc, Vc);
  transpose_v_kernel<<<dim3(32, 64, 4), dim3(32, 8), 0, stream>>>(Vc, VT);
  // P'[b][q][k] = exp((Q[b][q,:].K[b][k,:])/32), rowsum accumulated
  gemm_bt<EPI_QK><<<dim3(16, 16, 4), 256, 0, stream>>>(
      Qc, Kc, SP, 1024, 1024, 1024, 2048,
      2048L * 1024, 2048L * 1024, 2048L * 2048, RS, nullptr, nullptr);
  // out[b][q][e] = (P'[b][q,:] . VT[b][e,:]) / rowsum[b][q]
  gemm_bt<EPI_PV><<<dim3(8, 16, 4), 256, 0, stream>>>(
      SP, VT, out, 2048, 2048, 2048, 1024,
      2048L * 2048, 1024L * 2048, 2048L * 1024, RS, nullptr, nullptr);
}

// Round 5
// 252.474 us; speedup vs baseline: 1.2218x; 1.1613x over previous
//
#include <hip/hip_runtime.h>
#include <hip/hip_bf16.h>
#include <cstdio>

typedef __bf16  bf16x8 __attribute__((ext_vector_type(8)));
typedef float   f32x4  __attribute__((ext_vector_type(4)));
typedef unsigned short u16;
typedef u16     u16x8  __attribute__((ext_vector_type(8)));
typedef u16     u16x4  __attribute__((ext_vector_type(4)));

// ---------- helpers ----------

__device__ __forceinline__ void gld_lds16(const void* g, void* l) {
  // async global->LDS, 16B per lane; LDS dest is wave-uniform base + lane*16
  __builtin_amdgcn_global_load_lds(
      (const __attribute__((address_space(1))) unsigned int*)g,
      (__attribute__((address_space(3))) unsigned int*)l,
      16, 0, 0);
}

__device__ __forceinline__ u16 f2bf(float f) {
  union { float f; unsigned int u; } c{f};
  unsigned int u = c.u;
  u += 0x7fffu + ((u >> 16) & 1u);   // round-to-nearest-even
  return (u16)(u >> 16);
}

__device__ __forceinline__ float bf2f(u16 h) {
  union { unsigned int u; float f; } c{(unsigned int)h << 16};
  return c.f;
}

// ---------- prep: cast x -> bf16, pack/transpose weights, zero rowsums ----------
// grid: [0,4096) cast blocks, [4096,7168) weight tiles, 7168 = RS zero

__global__ __launch_bounds__(256) void prep_kernel(const float* __restrict__ x,
                                                   u16* __restrict__ xbf,
                                                   const float* __restrict__ w,
                                                   u16* __restrict__ wt,
                                                   float* __restrict__ rs) {
  __shared__ float tile[32][33];
  const int bid = blockIdx.x;
  if (bid < 4096) {
    const int i = (bid * 256 + threadIdx.x) * 8;
    float4 a = *(const float4*)(x + i);
    float4 b = *(const float4*)(x + i + 4);
    u16x8 r;
    r[0] = f2bf(a.x); r[1] = f2bf(a.y); r[2] = f2bf(a.z); r[3] = f2bf(a.w);
    r[4] = f2bf(b.x); r[5] = f2bf(b.y); r[6] = f2bf(b.z); r[7] = f2bf(b.w);
    *(u16x8*)(xbf + i) = r;
  } else if (bid < 7168) {
    // WT[s][e][d] = w[s][d][e], s in 0..2
    const int b2 = bid - 4096;
    const int s = b2 >> 10, r = b2 & 1023;
    const int e0 = (r & 31) * 32, d0 = (r >> 5) * 32;
    const int tx = threadIdx.x & 31, ty = threadIdx.x >> 5;
    const float* in = w + (size_t)s * 1048576;
#pragma unroll
    for (int j = 0; j < 4; ++j)
      tile[ty + j * 8][tx] = in[(size_t)(d0 + ty + j * 8) * 1024 + e0 + tx];
    __syncthreads();
    u16* o = wt + (size_t)s * 1048576;
#pragma unroll
    for (int j = 0; j < 4; ++j)
      o[(size_t)(e0 + ty + j * 8) * 1024 + d0 + tx] = f2bf(tile[tx][ty + j * 8]);
  } else {
    const float4 z = {0.f, 0.f, 0.f, 0.f};
#pragma unroll
    for (int j = 0; j < 8; ++j)
      ((float4*)rs)[threadIdx.x + j * 256] = z;  // 8192 floats
  }
}

// ---------- BT-GEMM: C[M,N] = A[M,K] * B[N,K]^T, bf16 in, fp32 acc ----------
// grid: (N/128, M/128, batch); block 256 (4 waves, 2x2 of 64x64); BK = 64.
//
// LDS tile: 128 rows x 64 bf16 (128 B/row, unpadded for global_load_lds).
// XOR-swizzle: 16B chunk c of row r lives at slot c ^ (r&7) -> every 8-lane
// b128 phase covers all 32 banks (verified: banks 4*l mod 32, width 4).
//
// Epilogues:
//  EPI_QKV: n0<2048 -> dense bf16 stores to Qc/Kc (ld 1024);
//           n0>=2048 (V slice) -> transpose 128x128 tile through LDS,
//           coalesced 16B stores into VT. V never hits HBM untransposed.
//  EPI_QK : store P' = exp(acc/32) bf16 (unnormalized), atomicAdd fp32 row sums
//  EPI_PV : fp32 store of acc / rowsum[row]

enum { EPI_QKV = 0, EPI_QK = 1, EPI_PV = 2 };

template <int EPI>
__global__ __launch_bounds__(256)
void gemm_bt(const u16* __restrict__ A, const u16* __restrict__ B,
             void* __restrict__ Cv, int K, int lda, int ldb, int ldc,
             long sA, long sB, long sC,
             float* __restrict__ rowsum, u16* __restrict__ auxK, u16* __restrict__ auxV) {
  // QKV variant needs 128x136 u16 for the V-transpose staging (union w/ As+Bs)
  constexpr int LDS_U16 = (EPI == EPI_QKV) ? (128 * 136) : (128 * 128);
  __shared__ __align__(16) u16 lds[LDS_U16];
  u16* As = lds;
  u16* Bs = lds + 128 * 64;

  const int t = threadIdx.x;
  const int w = t >> 6, l = t & 63;
  const int bz = blockIdx.z;
  const u16* Ab = A + (long)bz * sA;
  const u16* Bb = B + (long)bz * sB;
  const int m0 = blockIdx.y * 128, n0 = blockIdx.x * 128;
  const int wm = w & 1, wn = w >> 1;
  const int lr = l & 15, lq = l >> 4;
  const int srow = l >> 3;                             // staging: row within 8-row chunk
  const int scol = ((l & 7) ^ ((l >> 3) & 7)) * 8;     // staging: swizzled global chunk (u16)
  const int rsw = l & 7;                               // read-side swizzle key

  f32x4 acc[4][4] = {};

  for (int k0 = 0; k0 < K; k0 += 64) {
    __syncthreads();
#pragma unroll
    for (int c = 0; c < 4; ++c) {
      const int rb = (w * 4 + c) * 8;  // 4 waves x 4 calls x 8 rows = 128
      gld_lds16(Ab + (long)(m0 + rb + srow) * lda + k0 + scol, (void*)(As + rb * 64));
      gld_lds16(Bb + (long)(n0 + rb + srow) * ldb + k0 + scol, (void*)(Bs + rb * 64));
    }
    __syncthreads();
#pragma unroll
    for (int j = 0; j < 2; ++j) {
      bf16x8 af[4], bfr[4];
#pragma unroll
      for (int i = 0; i < 4; ++i) {
        const int ch = ((j * 4 + lq) ^ rsw) * 8;
        af[i]  = *(const bf16x8*)(As + (wm * 64 + i * 16 + lr) * 64 + ch);
        bfr[i] = *(const bf16x8*)(Bs + (wn * 64 + i * 16 + lr) * 64 + ch);
      }
#pragma unroll
      for (int mi = 0; mi < 4; ++mi)
#pragma unroll
        for (int ni = 0; ni < 4; ++ni)
          acc[mi][ni] = __builtin_amdgcn_mfma_f32_16x16x32_bf16(af[mi], bfr[ni], acc[mi][ni], 0, 0, 0);
    }
  }

  if (EPI == EPI_QKV && n0 >= 2048) {
    // ---- V slice: transpose 128x128 tile through LDS, store coalesced to VT ----
    u16* tt = lds;  // [128 cols][136 rows-padded] u16 = 34816 B
    __syncthreads();  // all frag reads done; safe to overwrite As/Bs
#pragma unroll
    for (int mi = 0; mi < 4; ++mi) {
      const int row0 = wm * 64 + mi * 16 + lq * 4;
#pragma unroll
      for (int ni = 0; ni < 4; ++ni) {
        const int col = wn * 64 + ni * 16 + lr;
        u16x4 v4;
#pragma unroll
        for (int i = 0; i < 4; ++i) v4[i] = f2bf(acc[mi][ni][i]);
        *(u16x4*)(tt + col * 136 + row0) = v4;   // 8B store, 8B-aligned
      }
    }
    __syncthreads();
    // readback: chunk = e-col * 16 + (k/8); 2048 chunks / 256 threads = 8 each
    const int e0 = n0 - 2048;
    const long bb = m0 >> 11;           // batch
    const int kbase = m0 & 2047;
    u16* vt_base = auxV + bb * 2097152;
#pragma unroll
    for (int q = 0; q < 8; ++q) {
      const int chunk = q * 256 + t;
      const int c = chunk >> 4, r0 = (chunk & 15) * 8;
      u16x8 v = *(const u16x8*)(tt + c * 136 + r0);      // b128, conflict-free
      *(u16x8*)(vt_base + (long)(e0 + c) * 2048 + kbase + r0) = v;  // coalesced
    }
    return;
  }

  // block-uniform output target for EPI_QKV (Q or K slice)
  u16* qkv_out = nullptr;
  int nl0 = 0;
  if (EPI == EPI_QKV) {
    qkv_out = (n0 < 1024) ? (u16*)Cv : auxK;
    nl0 = n0 & 1023;
  }

#pragma unroll
  for (int mi = 0; mi < 4; ++mi) {
#pragma unroll
    for (int i = 0; i < 4; ++i) {
      const int row = m0 + wm * 64 + mi * 16 + lq * 4 + i;
      float inv;
      if (EPI == EPI_PV) inv = 1.0f / rowsum[bz * 2048 + row];
      float rs = 0.f;
#pragma unroll
      for (int ni = 0; ni < 4; ++ni) {
        const float val = acc[mi][ni][i];
        if (EPI == EPI_QKV) {
          const int col_l = nl0 + wn * 64 + ni * 16 + lr;
          qkv_out[(long)row * 1024 + col_l] = f2bf(val);
        } else if (EPI == EPI_QK) {
          const int col = n0 + wn * 64 + ni * 16 + lr;
          const u16 h = f2bf(__expf(val * 0.03125f));  // unnormalized prob, bf16
          ((u16*)Cv)[(long)bz * sC + (long)row * ldc + col] = h;
          rs += bf2f(h);                                // sum the rounded value
        } else {  // EPI_PV
          const int col = n0 + wn * 64 + ni * 16 + lr;
          ((float*)Cv)[(long)bz * sC + (long)row * ldc + col] = val * inv;
        }
      }
      if (EPI == EPI_QK) {
        // reduce over the 16 lanes (lr) that share this row
        rs += __shfl_xor(rs, 1, 64);
        rs += __shfl_xor(rs, 2, 64);
        rs += __shfl_xor(rs, 4, 64);
        rs += __shfl_xor(rs, 8, 64);
        if (lr == 0) atomicAdd(rowsum + bz * 2048 + row, rs);
      }
    }
  }
}

// ---------- launch ----------

extern "C" void kernel_launch(void* const* d_in, const int* in_sizes, int n_in,
                              void* d_out, int out_size, void* d_ws, size_t ws_size,
                              hipStream_t stream) {
  (void)in_sizes; (void)n_in; (void)out_size;
  const float* x    = (const float*)d_in[0];
  const float* kern = (const float*)d_in[1];
  float* out = (float*)d_out;
  char* ws = (char*)d_ws;
  const size_t MB = 1024 * 1024;
  u16*   xbf  = (u16*)(ws);              // 16 MB: [8192][1024] bf16
  u16*   WT   = (u16*)(ws + 16 * MB);    //  6 MB: [3][1024][1024] bf16
  u16*   Qc   = (u16*)(ws + 22 * MB);    // 16 MB: [8192][1024] bf16
  u16*   Kc   = (u16*)(ws + 38 * MB);    // 16 MB: [8192][1024] bf16
  u16*   VT   = (u16*)(ws + 54 * MB);    // 16 MB: [4][1024e][2048k] bf16
  u16*   SP   = (u16*)(ws + 70 * MB);    // 32 MB: [4][2048][2048] bf16 unnormalized probs
  float* RS   = (float*)(ws + 102 * MB); // 32 KB: [4][2048] fp32 row sums
  if (ws_size < 102 * MB + 32768)
    fprintf(stderr, "WARNING: ws_size %zu too small\n", ws_size);

  prep_kernel<<<7169, 256, 0, stream>>>(x, xbf, kern, WT, RS);
  // Q[m][e], K[m][e] dense; V slice transposed in-epilogue into VT
  gemm_bt<EPI_QKV><<<dim3(24, 64, 1), 256, 0, stream>>>(
      xbf, WT, Qc, 1024, 1024, 1024, 1024, 0, 0, 0, nullptr, Kc, VT);
  // P'[b][q][k] = exp((Q[b][q,:].K[b][k,:])/32), rowsum accumulated
  gemm_bt<EPI_QK><<<dim3(16, 16, 4), 256, 0, stream>>>(
      Qc, Kc, SP, 1024, 1024, 1024, 2048,
      2048L * 1024, 2048L * 1024, 2048L * 2048, RS, nullptr, nullptr);
  // out[b][q][e] = (P'[b][q,:] . VT[b][e,:]) / rowsum[b][q]
  gemm_bt<EPI_PV><<<dim3(8, 16, 4), 256, 0, stream>>>(
      SP, VT, out, 2048, 2048, 2048, 1024,
      2048L * 2048, 1024L * 2048, 2048L * 1024, RS, nullptr, nullptr);
}